// Round 1
// baseline (133.342 us; speedup 1.0000x reference)
//
#include <hip/hip_runtime.h>

// Chamfer distance, direction-symmetric kernel.
// For each query point p in P, min over target points q in Q of ||p-q||^2.
// Grid: x = (B*Np / ROWS_PER_BLOCK) row-tiles (each within one batch),
//       y = Mp / SLICE target slices. Cross-slice combine via atomicMin on
//       uint bit-pattern (valid for non-negative floats).

#define SLICE 512           // target points staged in LDS per block (6 KB)
#define ROWS_PER_BLOCK 512  // 256 threads * 2 query rows each

__global__ __launch_bounds__(256)
void chamfer_dir_kernel(const float* __restrict__ P,   // query  [B*Np*3]
                        const float* __restrict__ Q,   // target [B*Mp*3]
                        unsigned int* __restrict__ out,// [B*Np] float-bits
                        int Np, int Mp) {
    __shared__ float lds[SLICE * 3];
    const int tid = threadIdx.x;
    const int rowBase = blockIdx.x * ROWS_PER_BLOCK;   // flat over B*Np
    const int b = rowBase / Np;                        // batch (exact: ROWS_PER_BLOCK | Np)
    const int slice0 = blockIdx.y * SLICE;

    // Cooperative float4 staging of the target slice: 512*3 floats = 384 float4
    const float4* src = (const float4*)(Q + ((size_t)b * Mp + slice0) * 3);
    float4* dst = (float4*)lds;
    #pragma unroll
    for (int i = tid; i < (SLICE * 3) / 4; i += 256) dst[i] = src[i];

    // Load this thread's two query points (tiny, L2-resident)
    const int q0 = rowBase + tid;
    const int q1 = q0 + 256;
    const float* p0 = P + (size_t)q0 * 3;
    const float* p1 = P + (size_t)q1 * 3;
    const float x0 = p0[0], y0 = p0[1], z0 = p0[2];
    const float x1 = p1[0], y1 = p1[1], z1 = p1[2];

    __syncthreads();

    float best0 = 3.0e38f, best1 = 3.0e38f;
    #pragma unroll 8
    for (int j = 0; j < SLICE; ++j) {
        const float sx = lds[3*j+0];   // uniform address -> LDS broadcast
        const float sy = lds[3*j+1];
        const float sz = lds[3*j+2];
        const float dx0 = x0 - sx, dy0 = y0 - sy, dz0 = z0 - sz;
        const float d0  = fmaf(dx0, dx0, fmaf(dy0, dy0, dz0 * dz0));
        const float dx1 = x1 - sx, dy1 = y1 - sy, dz1 = z1 - sz;
        const float d1  = fmaf(dx1, dx1, fmaf(dy1, dy1, dz1 * dz1));
        best0 = fminf(best0, d0);
        best1 = fminf(best1, d1);
    }

    atomicMin(out + q0, __float_as_uint(best0));
    atomicMin(out + q1, __float_as_uint(best1));
}

extern "C" void kernel_launch(void* const* d_in, const int* in_sizes, int n_in,
                              void* d_out, int out_size, void* d_ws, size_t ws_size,
                              hipStream_t stream) {
    const float* in1 = (const float*)d_in[0];   // [B, N, 3]
    const float* in2 = (const float*)d_in[1];   // [B, M, 3]
    const int B = 8;
    const int N = in_sizes[0] / (B * 3);
    const int M = in_sizes[1] / (B * 3);
    unsigned int* out = (unsigned int*)d_out;

    // Sentinel init: 0x7F7F7F7F = 3.39e38f (also max-uint-ish for atomicMin path)
    hipMemsetAsync(d_out, 0x7F, (size_t)out_size * sizeof(float), stream);

    // dist1: queries = input1, targets = input2
    dim3 g1(B * N / ROWS_PER_BLOCK, M / SLICE);
    chamfer_dir_kernel<<<g1, 256, 0, stream>>>(in1, in2, out, N, M);

    // dist2: queries = input2, targets = input1
    dim3 g2(B * M / ROWS_PER_BLOCK, N / SLICE);
    chamfer_dir_kernel<<<g2, 256, 0, stream>>>(in2, in1, out + (size_t)B * N, M, N);
}

// Round 2
// 95.951 us; speedup vs baseline: 1.3897x; 1.3897x over previous
//
#include <hip/hip_runtime.h>

// Chamfer distance, direction-symmetric kernel, decomposed-distance form:
//   d(p,q) = ||p||^2 + (||q||^2 - 2 p.q)
// Track best' = min_q(||q||^2 - 2 p.q); add ||p||^2 once at the end.
// Inner loop: 3 FMA per pair + paired v_min3 merge => ~3.5 VALU instr/pair.
// Targets staged in LDS as float4 (x,y,z,||q||^2): one ds_read_b128/target,
// uniform address -> broadcast, no bank conflicts.
// Cross-slice combine via atomicMin on uint bit-pattern (valid for floats
// that are >= 0 up to ~1e-5 rounding; candidate spread near 0 << threshold).

#define SLICE 512           // target points staged in LDS per block (8 KB)
#define ROWS_PER_BLOCK 512  // 256 threads * 2 query rows each

__global__ __launch_bounds__(256)
void chamfer_dir_kernel(const float* __restrict__ P,   // query  [B*Np*3]
                        const float* __restrict__ Q,   // target [B*Mp*3]
                        unsigned int* __restrict__ out,// [B*Np] float-bits
                        int Np, int Mp) {
    __shared__ float4 lds[SLICE];
    const int tid = threadIdx.x;
    const int rowBase = blockIdx.x * ROWS_PER_BLOCK;   // flat over B*Np
    const int b = rowBase / Np;                        // exact: ROWS_PER_BLOCK | Np
    const int slice0 = blockIdx.y * SLICE;

    // Stage targets: (x, y, z, ||q||^2) per point, 2 points per thread.
    const float* qs = Q + ((size_t)b * Mp + slice0) * 3;
    #pragma unroll
    for (int i = tid; i < SLICE; i += 256) {
        const float x = qs[3*i+0], y = qs[3*i+1], z = qs[3*i+2];
        lds[i] = make_float4(x, y, z, fmaf(x, x, fmaf(y, y, z * z)));
    }

    // This thread's two query points: precompute -2*p and ||p||^2.
    const int q0 = rowBase + tid;
    const int q1 = q0 + 256;
    const float* p0 = P + (size_t)q0 * 3;
    const float* p1 = P + (size_t)q1 * 3;
    const float x0 = p0[0], y0 = p0[1], z0 = p0[2];
    const float x1 = p1[0], y1 = p1[1], z1 = p1[2];
    const float m2x0 = -2.0f * x0, m2y0 = -2.0f * y0, m2z0 = -2.0f * z0;
    const float m2x1 = -2.0f * x1, m2y1 = -2.0f * y1, m2z1 = -2.0f * z1;
    const float sqp0 = fmaf(x0, x0, fmaf(y0, y0, z0 * z0));
    const float sqp1 = fmaf(x1, x1, fmaf(y1, y1, z1 * z1));

    __syncthreads();

    float best0 = 3.0e38f, best1 = 3.0e38f;
    #pragma unroll 4
    for (int j = 0; j < SLICE; j += 2) {
        const float4 a = lds[j];
        const float4 c = lds[j + 1];
        const float d00 = fmaf(m2x0, a.x, fmaf(m2y0, a.y, fmaf(m2z0, a.z, a.w)));
        const float d01 = fmaf(m2x0, c.x, fmaf(m2y0, c.y, fmaf(m2z0, c.z, c.w)));
        best0 = fminf(fminf(d00, d01), best0);   // -> v_min3_f32
        const float d10 = fmaf(m2x1, a.x, fmaf(m2y1, a.y, fmaf(m2z1, a.z, a.w)));
        const float d11 = fmaf(m2x1, c.x, fmaf(m2y1, c.y, fmaf(m2z1, c.z, c.w)));
        best1 = fminf(fminf(d10, d11), best1);   // -> v_min3_f32
    }

    atomicMin(out + q0, __float_as_uint(best0 + sqp0));
    atomicMin(out + q1, __float_as_uint(best1 + sqp1));
}

extern "C" void kernel_launch(void* const* d_in, const int* in_sizes, int n_in,
                              void* d_out, int out_size, void* d_ws, size_t ws_size,
                              hipStream_t stream) {
    const float* in1 = (const float*)d_in[0];   // [B, N, 3]
    const float* in2 = (const float*)d_in[1];   // [B, M, 3]
    const int B = 8;
    const int N = in_sizes[0] / (B * 3);
    const int M = in_sizes[1] / (B * 3);
    unsigned int* out = (unsigned int*)d_out;

    // Sentinel init: 0x7F7F7F7F = 3.39e38f
    hipMemsetAsync(d_out, 0x7F, (size_t)out_size * sizeof(float), stream);

    // dist1: queries = input1, targets = input2
    dim3 g1(B * N / ROWS_PER_BLOCK, M / SLICE);
    chamfer_dir_kernel<<<g1, 256, 0, stream>>>(in1, in2, out, N, M);

    // dist2: queries = input2, targets = input1
    dim3 g2(B * M / ROWS_PER_BLOCK, N / SLICE);
    chamfer_dir_kernel<<<g2, 256, 0, stream>>>(in2, in1, out + (size_t)B * N, M, N);
}

// Round 3
// 75.592 us; speedup vs baseline: 1.7640x; 1.2693x over previous
//
#include <hip/hip_runtime.h>

// Chamfer distance via bf16 split-MFMA.
//   d(p,q') = ||p||^2 + (||q'||^2 - 2 p.q')
// The parenthesized term is a rank-16 GEMM in bf16 hi/lo-split form:
//   K-slots A(target): [-2x'h,-2x'l,-2x'h,-2x'l, -2y'h,..., -2z'h,..., sq'h, sq'l, 0,0]
//   K-slots B(query) : [  xh,   xh,   xl,   xl,   yh, ...,   zh, ...,  1.0, 1.0, 0,0]
// One v_mfma_f32_32x32x16_bf16 = 32 targets x 32 queries = 1024 pairs (~8 cy),
// followed by 8 v_min3_f32 folds per lane (16 D-regs = 16 targets, col=query).
// Targets prepacked (pre-pass kernel) into MFMA A-fragment order per 32-target
// tile so the inner ds_read_b128 is linear lane*16 (conflict-free).
// Cross-slice/cross-wave combine: atomicMin on uint bits (values clamped >= 0).

typedef __attribute__((ext_vector_type(8))) short  s16x8;
typedef __attribute__((ext_vector_type(16))) float f32x16;

#define TSLICE 1024   // targets staged in LDS per block (32 KB packed)
#define QPB    512    // queries per block (4 waves x 128)
#define QPW    128    // queries per wave (4 frags of 32)

// ---------- bf16 split helpers (bit-level, RNE) ----------
__device__ inline unsigned int bf16bits(float v, float &hival) {
    unsigned int u = __float_as_uint(v);
    unsigned int r = (u + 0x7FFFu + ((u >> 16) & 1u)) >> 16;
    hival = __uint_as_float(r << 16);
    return r;
}

// ---------- pre-pass: pack one input both as-target (A) and as-query (B) ----------
__global__ __launch_bounds__(256)
void pack_kernel(const float* __restrict__ src, ushort* __restrict__ pA,
                 ushort* __restrict__ pB, float* __restrict__ sq, int npts) {
    const int p = blockIdx.x * 256 + threadIdx.x;
    if (p >= npts) return;
    const float x = src[3*p+0], y = src[3*p+1], z = src[3*p+2];
    float xhf, xlf, yhf, ylf, zhf, zlf, shf, tmp;
    const ushort xh = (ushort)bf16bits(x, xhf);
    const ushort xl = (ushort)bf16bits(x - xhf, xlf);
    const ushort yh = (ushort)bf16bits(y, yhf);
    const ushort yl = (ushort)bf16bits(y - yhf, ylf);
    const ushort zh = (ushort)bf16bits(z, zhf);
    const ushort zl = (ushort)bf16bits(z - zhf, zlf);
    const float s = fmaf(x, x, fmaf(y, y, z * z));
    const ushort sh = (ushort)bf16bits(s, shf);
    const ushort sl = (ushort)bf16bits(s - shf, tmp);
    const ushort m2xh = (ushort)bf16bits(-2.0f * xhf, tmp);
    const ushort m2xl = (ushort)bf16bits(-2.0f * xlf, tmp);
    const ushort m2yh = (ushort)bf16bits(-2.0f * yhf, tmp);
    const ushort m2yl = (ushort)bf16bits(-2.0f * ylf, tmp);
    const ushort m2zh = (ushort)bf16bits(-2.0f * zhf, tmp);
    const ushort m2zl = (ushort)bf16bits(-2.0f * zlf, tmp);
    const ushort ONE = 0x3F80;

    const s16x8 a0 = {(short)m2xh,(short)m2xl,(short)m2xh,(short)m2xl,
                      (short)m2yh,(short)m2yl,(short)m2yh,(short)m2yl};
    const s16x8 a1 = {(short)m2zh,(short)m2zl,(short)m2zh,(short)m2zl,
                      (short)sh,  (short)sl,  0, 0};
    const s16x8 b0 = {(short)xh,(short)xh,(short)xl,(short)xl,
                      (short)yh,(short)yh,(short)yl,(short)yl};
    const s16x8 b1 = {(short)zh,(short)zh,(short)zl,(short)zl,
                      (short)ONE,(short)ONE, 0, 0};

    s16x8* A8 = (s16x8*)pA;
    s16x8* B8 = (s16x8*)pB;
    // A: fragment-linear per 32-target tile: chunk = tilebase*64 + khalf*32 + row
    const int c0 = (p & ~31) * 2 + (p & 31);
    A8[c0]      = a0;   // k-slots 0-7  (lanes 0-31)
    A8[c0 + 32] = a1;   // k-slots 8-15 (lanes 32-63)
    // B: point-major
    B8[2*p]     = b0;
    B8[2*p + 1] = b1;
    sq[p] = s;
}

// ---------- main MFMA kernel, one direction ----------
__global__ __launch_bounds__(256)
void chamfer_mfma_kernel(const ushort* __restrict__ pA,   // targets, tile-layout
                         const ushort* __restrict__ pB,   // queries, point-major
                         const float*  __restrict__ sqq,  // queries' ||p||^2 fp32
                         unsigned int* __restrict__ out,  // [B*Np] float bits
                         int Np, int Mp) {
    __shared__ s16x8 lds8[TSLICE * 2];   // 32 KB
    const int tid  = threadIdx.x;
    const int lane = tid & 63;
    const int wid  = tid >> 6;
    const int qblock = blockIdx.x * QPB;        // flat over B*Np (QPB | Np)
    const int b = qblock / Np;
    const size_t gchunk = ((size_t)b * Mp + (size_t)blockIdx.y * TSLICE) * 2;
    const s16x8* gA = (const s16x8*)pA + gchunk;
    for (int i = tid; i < TSLICE * 2; i += 256) lds8[i] = gA[i];

    // B fragments: 4 x 32 queries, loop-invariant in registers
    const int qw = qblock + wid * QPW;
    s16x8 bf[4];
    #pragma unroll
    for (int f = 0; f < 4; ++f) {
        const int q = qw + f * 32 + (lane & 31);
        bf[f] = *(const s16x8*)(pB + (size_t)q * 16 + (size_t)(lane >> 5) * 8);
    }
    __syncthreads();

    const f32x16 cz = {0.f,0.f,0.f,0.f,0.f,0.f,0.f,0.f,
                       0.f,0.f,0.f,0.f,0.f,0.f,0.f,0.f};
    float bests[4] = {3.0e38f, 3.0e38f, 3.0e38f, 3.0e38f};

    const int NT = TSLICE / 32;
    s16x8 a = lds8[lane];
    for (int t = 0; t < NT; ++t) {
        const int tn = (t + 1 < NT) ? (t + 1) : t;
        const s16x8 an = lds8[tn * 64 + lane];          // prefetch next tile
        #pragma unroll
        for (int f = 0; f < 4; ++f) {
            const f32x16 d = __builtin_amdgcn_mfma_f32_32x32x16_bf16(a, bf[f], cz, 0, 0, 0);
            const float a0 = fminf(fminf(d[0],  d[1]),  d[2]);
            const float a1 = fminf(fminf(d[3],  d[4]),  d[5]);
            const float a2 = fminf(fminf(d[6],  d[7]),  d[8]);
            const float a3 = fminf(fminf(d[9],  d[10]), d[11]);
            const float a4 = fminf(fminf(d[12], d[13]), d[14]);
            const float a5 = fminf(fminf(a0, a1), d[15]);
            const float a6 = fminf(fminf(a2, a3), a4);
            bests[f] = fminf(fminf(a5, a6), bests[f]);
        }
        a = an;
    }

    #pragma unroll
    for (int f = 0; f < 4; ++f) {
        float v = fminf(bests[f], __shfl_xor(bests[f], 32));  // merge row halves
        const int q = qw + f * 32 + (lane & 31);
        v = fmaxf(v + sqq[q], 0.0f);                          // clamp: keep >= 0
        if (lane < 32) atomicMin(out + q, __float_as_uint(v));
    }
}

// ---------- fallback (round-2 VALU kernel) if ws too small ----------
#define FSLICE 512
#define FROWS  512
__global__ __launch_bounds__(256)
void chamfer_dir_kernel(const float* __restrict__ P, const float* __restrict__ Q,
                        unsigned int* __restrict__ out, int Np, int Mp) {
    __shared__ float4 lds[FSLICE];
    const int tid = threadIdx.x;
    const int rowBase = blockIdx.x * FROWS;
    const int b = rowBase / Np;
    const int slice0 = blockIdx.y * FSLICE;
    const float* qs = Q + ((size_t)b * Mp + slice0) * 3;
    #pragma unroll
    for (int i = tid; i < FSLICE; i += 256) {
        const float x = qs[3*i+0], y = qs[3*i+1], z = qs[3*i+2];
        lds[i] = make_float4(x, y, z, fmaf(x, x, fmaf(y, y, z * z)));
    }
    const int q0 = rowBase + tid, q1 = q0 + 256;
    const float* p0 = P + (size_t)q0 * 3;
    const float* p1 = P + (size_t)q1 * 3;
    const float x0=p0[0], y0=p0[1], z0=p0[2], x1=p1[0], y1=p1[1], z1=p1[2];
    const float m2x0=-2*x0, m2y0=-2*y0, m2z0=-2*z0, m2x1=-2*x1, m2y1=-2*y1, m2z1=-2*z1;
    const float sqp0 = fmaf(x0,x0,fmaf(y0,y0,z0*z0));
    const float sqp1 = fmaf(x1,x1,fmaf(y1,y1,z1*z1));
    __syncthreads();
    float best0 = 3.0e38f, best1 = 3.0e38f;
    #pragma unroll 4
    for (int j = 0; j < FSLICE; j += 2) {
        const float4 a = lds[j], c = lds[j+1];
        const float d00 = fmaf(m2x0,a.x,fmaf(m2y0,a.y,fmaf(m2z0,a.z,a.w)));
        const float d01 = fmaf(m2x0,c.x,fmaf(m2y0,c.y,fmaf(m2z0,c.z,c.w)));
        best0 = fminf(fminf(d00,d01), best0);
        const float d10 = fmaf(m2x1,a.x,fmaf(m2y1,a.y,fmaf(m2z1,a.z,a.w)));
        const float d11 = fmaf(m2x1,c.x,fmaf(m2y1,c.y,fmaf(m2z1,c.z,c.w)));
        best1 = fminf(fminf(d10,d11), best1);
    }
    atomicMin(out + q0, __float_as_uint(fmaxf(best0 + sqp0, 0.f)));
    atomicMin(out + q1, __float_as_uint(fmaxf(best1 + sqp1, 0.f)));
}

extern "C" void kernel_launch(void* const* d_in, const int* in_sizes, int n_in,
                              void* d_out, int out_size, void* d_ws, size_t ws_size,
                              hipStream_t stream) {
    const float* in1 = (const float*)d_in[0];   // [B, N, 3]
    const float* in2 = (const float*)d_in[1];   // [B, M, 3]
    const int B = 8;
    const int N = in_sizes[0] / (B * 3);
    const int M = in_sizes[1] / (B * 3);
    const int P1 = B * N, P2 = B * M;
    unsigned int* out = (unsigned int*)d_out;

    hipMemsetAsync(d_out, 0x7F, (size_t)out_size * sizeof(float), stream);

    const size_t packBytes1 = (size_t)P1 * 32, packBytes2 = (size_t)P2 * 32;
    const size_t need = 2*packBytes1 + 2*packBytes2 + (size_t)(P1+P2)*4;

    if (ws_size >= need) {
        char* w = (char*)d_ws;
        ushort* A1 = (ushort*)(w);
        ushort* B1 = (ushort*)(w + packBytes1);
        ushort* A2 = (ushort*)(w + 2*packBytes1);
        ushort* B2 = (ushort*)(w + 2*packBytes1 + packBytes2);
        float*  S1 = (float*) (w + 2*packBytes1 + 2*packBytes2);
        float*  S2 = (float*) (w + 2*packBytes1 + 2*packBytes2 + (size_t)P1*4);

        pack_kernel<<<(P1 + 255)/256, 256, 0, stream>>>(in1, A1, B1, S1, P1);
        pack_kernel<<<(P2 + 255)/256, 256, 0, stream>>>(in2, A2, B2, S2, P2);

        // dist1: queries = input1 (B1,S1), targets = input2 (A2)
        dim3 g1(P1 / QPB, M / TSLICE);
        chamfer_mfma_kernel<<<g1, 256, 0, stream>>>(A2, B1, S1, out, N, M);
        // dist2: queries = input2 (B2,S2), targets = input1 (A1)
        dim3 g2(P2 / QPB, N / TSLICE);
        chamfer_mfma_kernel<<<g2, 256, 0, stream>>>(A1, B2, S2, out + P1, M, N);
    } else {
        dim3 g1(P1 / FROWS, M / FSLICE);
        chamfer_dir_kernel<<<g1, 256, 0, stream>>>(in1, in2, out, N, M);
        dim3 g2(P2 / FROWS, N / FSLICE);
        chamfer_dir_kernel<<<g2, 256, 0, stream>>>(in2, in1, out + P1, M, N);
    }
}

// Round 4
// 69.570 us; speedup vs baseline: 1.9167x; 1.0866x over previous
//
#include <hip/hip_runtime.h>

// Chamfer distance via bf16 split-MFMA.
//   d(p,q') = ||p||^2 + (||q'||^2 - 2 p.q')
// The parenthesized term is a rank-16 GEMM in bf16 hi/lo-split form:
//   K-slots A(target): [-2x'h,-2x'l,-2x'h,-2x'l, -2y'h,..., -2z'h,..., sq'h, sq'l, 0,0]
//   K-slots B(query) : [  xh,   xh,   xl,   xl,   yh, ...,   zh, ...,  1.0, 1.0, 0,0]
// One v_mfma_f32_32x32x16_bf16 = 32 targets x 32 queries = 1024 pairs (~8 cy),
// followed by 8 v_min3_f32 folds per lane (16 D-regs = 16 targets, col=query).
// Targets prepacked (pre-pass kernel) into MFMA A-fragment order per 32-target
// tile so the inner ds_read_b128 is linear lane*16 (conflict-free).
// Cross-slice/cross-wave combine: atomicMin on uint bits (values clamped >= 0).
// Sentinel init of d_out is folded into the pack kernels (a 512KB
// hipMemsetAsync cost 41 us serial in round 3 -- latency-bound fill).

typedef __attribute__((ext_vector_type(8))) short  s16x8;
typedef __attribute__((ext_vector_type(16))) float f32x16;

#define TSLICE 1024   // targets staged in LDS per block (32 KB packed)
#define QPB    512    // queries per block (4 waves x 128)
#define QPW    128    // queries per wave (4 frags of 32)

// ---------- bf16 split helpers (bit-level, RNE) ----------
__device__ inline unsigned int bf16bits(float v, float &hival) {
    unsigned int u = __float_as_uint(v);
    unsigned int r = (u + 0x7FFFu + ((u >> 16) & 1u)) >> 16;
    hival = __uint_as_float(r << 16);
    return r;
}

// ---------- pre-pass: pack one input both as-target (A) and as-query (B) ----
// Also writes the atomicMin sentinel for this input's slice of d_out.
__global__ __launch_bounds__(256)
void pack_kernel(const float* __restrict__ src, ushort* __restrict__ pA,
                 ushort* __restrict__ pB, float* __restrict__ sq,
                 unsigned int* __restrict__ outInit, int npts) {
    const int p = blockIdx.x * 256 + threadIdx.x;
    if (p >= npts) return;
    outInit[p] = 0x7F7F7F7Fu;                 // 3.39e38f sentinel
    const float x = src[3*p+0], y = src[3*p+1], z = src[3*p+2];
    float xhf, xlf, yhf, ylf, zhf, zlf, shf, tmp;
    const ushort xh = (ushort)bf16bits(x, xhf);
    const ushort xl = (ushort)bf16bits(x - xhf, xlf);
    const ushort yh = (ushort)bf16bits(y, yhf);
    const ushort yl = (ushort)bf16bits(y - yhf, ylf);
    const ushort zh = (ushort)bf16bits(z, zhf);
    const ushort zl = (ushort)bf16bits(z - zhf, zlf);
    const float s = fmaf(x, x, fmaf(y, y, z * z));
    const ushort sh = (ushort)bf16bits(s, shf);
    const ushort sl = (ushort)bf16bits(s - shf, tmp);
    const ushort m2xh = (ushort)bf16bits(-2.0f * xhf, tmp);
    const ushort m2xl = (ushort)bf16bits(-2.0f * xlf, tmp);
    const ushort m2yh = (ushort)bf16bits(-2.0f * yhf, tmp);
    const ushort m2yl = (ushort)bf16bits(-2.0f * ylf, tmp);
    const ushort m2zh = (ushort)bf16bits(-2.0f * zhf, tmp);
    const ushort m2zl = (ushort)bf16bits(-2.0f * zlf, tmp);
    const ushort ONE = 0x3F80;

    const s16x8 a0 = {(short)m2xh,(short)m2xl,(short)m2xh,(short)m2xl,
                      (short)m2yh,(short)m2yl,(short)m2yh,(short)m2yl};
    const s16x8 a1 = {(short)m2zh,(short)m2zl,(short)m2zh,(short)m2zl,
                      (short)sh,  (short)sl,  0, 0};
    const s16x8 b0 = {(short)xh,(short)xh,(short)xl,(short)xl,
                      (short)yh,(short)yh,(short)yl,(short)yl};
    const s16x8 b1 = {(short)zh,(short)zh,(short)zl,(short)zl,
                      (short)ONE,(short)ONE, 0, 0};

    s16x8* A8 = (s16x8*)pA;
    s16x8* B8 = (s16x8*)pB;
    // A: fragment-linear per 32-target tile: chunk = tilebase*64 + khalf*32 + row
    const int c0 = (p & ~31) * 2 + (p & 31);
    A8[c0]      = a0;   // k-slots 0-7  (lanes 0-31)
    A8[c0 + 32] = a1;   // k-slots 8-15 (lanes 32-63)
    // B: point-major
    B8[2*p]     = b0;
    B8[2*p + 1] = b1;
    sq[p] = s;
}

// ---------- main MFMA kernel, one direction ----------
__global__ __launch_bounds__(256)
void chamfer_mfma_kernel(const ushort* __restrict__ pA,   // targets, tile-layout
                         const ushort* __restrict__ pB,   // queries, point-major
                         const float*  __restrict__ sqq,  // queries' ||p||^2 fp32
                         unsigned int* __restrict__ out,  // [B*Np] float bits
                         int Np, int Mp) {
    __shared__ s16x8 lds8[TSLICE * 2];   // 32 KB
    const int tid  = threadIdx.x;
    const int lane = tid & 63;
    const int wid  = tid >> 6;
    const int qblock = blockIdx.x * QPB;        // flat over B*Np (QPB | Np)
    const int b = qblock / Np;
    const size_t gchunk = ((size_t)b * Mp + (size_t)blockIdx.y * TSLICE) * 2;
    const s16x8* gA = (const s16x8*)pA + gchunk;
    for (int i = tid; i < TSLICE * 2; i += 256) lds8[i] = gA[i];

    // B fragments: 4 x 32 queries, loop-invariant in registers
    const int qw = qblock + wid * QPW;
    s16x8 bf[4];
    #pragma unroll
    for (int f = 0; f < 4; ++f) {
        const int q = qw + f * 32 + (lane & 31);
        bf[f] = *(const s16x8*)(pB + (size_t)q * 16 + (size_t)(lane >> 5) * 8);
    }
    __syncthreads();

    const f32x16 cz = {0.f,0.f,0.f,0.f,0.f,0.f,0.f,0.f,
                       0.f,0.f,0.f,0.f,0.f,0.f,0.f,0.f};
    float bests[4] = {3.0e38f, 3.0e38f, 3.0e38f, 3.0e38f};

    const int NT = TSLICE / 32;
    s16x8 a = lds8[lane];
    for (int t = 0; t < NT; ++t) {
        const int tn = (t + 1 < NT) ? (t + 1) : t;
        const s16x8 an = lds8[tn * 64 + lane];          // prefetch next tile
        #pragma unroll
        for (int f = 0; f < 4; ++f) {
            const f32x16 d = __builtin_amdgcn_mfma_f32_32x32x16_bf16(a, bf[f], cz, 0, 0, 0);
            const float a0 = fminf(fminf(d[0],  d[1]),  d[2]);
            const float a1 = fminf(fminf(d[3],  d[4]),  d[5]);
            const float a2 = fminf(fminf(d[6],  d[7]),  d[8]);
            const float a3 = fminf(fminf(d[9],  d[10]), d[11]);
            const float a4 = fminf(fminf(d[12], d[13]), d[14]);
            const float a5 = fminf(fminf(a0, a1), d[15]);
            const float a6 = fminf(fminf(a2, a3), a4);
            bests[f] = fminf(fminf(a5, a6), bests[f]);
        }
        a = an;
    }

    #pragma unroll
    for (int f = 0; f < 4; ++f) {
        float v = fminf(bests[f], __shfl_xor(bests[f], 32));  // merge row halves
        const int q = qw + f * 32 + (lane & 31);
        v = fmaxf(v + sqq[q], 0.0f);                          // clamp: keep >= 0
        if (lane < 32) atomicMin(out + q, __float_as_uint(v));
    }
}

// ---------- fallback (round-2 VALU kernel) if ws too small ----------
#define FSLICE 512
#define FROWS  512
__global__ __launch_bounds__(256)
void chamfer_dir_kernel(const float* __restrict__ P, const float* __restrict__ Q,
                        unsigned int* __restrict__ out, int Np, int Mp) {
    __shared__ float4 lds[FSLICE];
    const int tid = threadIdx.x;
    const int rowBase = blockIdx.x * FROWS;
    const int b = rowBase / Np;
    const int slice0 = blockIdx.y * FSLICE;
    const float* qs = Q + ((size_t)b * Mp + slice0) * 3;
    #pragma unroll
    for (int i = tid; i < FSLICE; i += 256) {
        const float x = qs[3*i+0], y = qs[3*i+1], z = qs[3*i+2];
        lds[i] = make_float4(x, y, z, fmaf(x, x, fmaf(y, y, z * z)));
    }
    const int q0 = rowBase + tid, q1 = q0 + 256;
    const float* p0 = P + (size_t)q0 * 3;
    const float* p1 = P + (size_t)q1 * 3;
    const float x0=p0[0], y0=p0[1], z0=p0[2], x1=p1[0], y1=p1[1], z1=p1[2];
    const float m2x0=-2*x0, m2y0=-2*y0, m2z0=-2*z0, m2x1=-2*x1, m2y1=-2*y1, m2z1=-2*z1;
    const float sqp0 = fmaf(x0,x0,fmaf(y0,y0,z0*z0));
    const float sqp1 = fmaf(x1,x1,fmaf(y1,y1,z1*z1));
    __syncthreads();
    float best0 = 3.0e38f, best1 = 3.0e38f;
    #pragma unroll 4
    for (int j = 0; j < FSLICE; j += 2) {
        const float4 a = lds[j], c = lds[j+1];
        const float d00 = fmaf(m2x0,a.x,fmaf(m2y0,a.y,fmaf(m2z0,a.z,a.w)));
        const float d01 = fmaf(m2x0,c.x,fmaf(m2y0,c.y,fmaf(m2z0,c.z,c.w)));
        best0 = fminf(fminf(d00,d01), best0);
        const float d10 = fmaf(m2x1,a.x,fmaf(m2y1,a.y,fmaf(m2z1,a.z,a.w)));
        const float d11 = fmaf(m2x1,c.x,fmaf(m2y1,c.y,fmaf(m2z1,c.z,c.w)));
        best1 = fminf(fminf(d10,d11), best1);
    }
    atomicMin(out + q0, __float_as_uint(fmaxf(best0 + sqp0, 0.f)));
    atomicMin(out + q1, __float_as_uint(fmaxf(best1 + sqp1, 0.f)));
}

extern "C" void kernel_launch(void* const* d_in, const int* in_sizes, int n_in,
                              void* d_out, int out_size, void* d_ws, size_t ws_size,
                              hipStream_t stream) {
    const float* in1 = (const float*)d_in[0];   // [B, N, 3]
    const float* in2 = (const float*)d_in[1];   // [B, M, 3]
    const int B = 8;
    const int N = in_sizes[0] / (B * 3);
    const int M = in_sizes[1] / (B * 3);
    const int P1 = B * N, P2 = B * M;
    unsigned int* out = (unsigned int*)d_out;

    const size_t packBytes1 = (size_t)P1 * 32, packBytes2 = (size_t)P2 * 32;
    const size_t need = 2*packBytes1 + 2*packBytes2 + (size_t)(P1+P2)*4;

    if (ws_size >= need) {
        char* w = (char*)d_ws;
        ushort* A1 = (ushort*)(w);
        ushort* B1 = (ushort*)(w + packBytes1);
        ushort* A2 = (ushort*)(w + 2*packBytes1);
        ushort* B2 = (ushort*)(w + 2*packBytes1 + packBytes2);
        float*  S1 = (float*) (w + 2*packBytes1 + 2*packBytes2);
        float*  S2 = (float*) (w + 2*packBytes1 + 2*packBytes2 + (size_t)P1*4);

        // pack + sentinel-init each direction's slice of d_out
        pack_kernel<<<(P1 + 255)/256, 256, 0, stream>>>(in1, A1, B1, S1, out, P1);
        pack_kernel<<<(P2 + 255)/256, 256, 0, stream>>>(in2, A2, B2, S2, out + P1, P2);

        // dist1: queries = input1 (B1,S1), targets = input2 (A2)
        dim3 g1(P1 / QPB, M / TSLICE);
        chamfer_mfma_kernel<<<g1, 256, 0, stream>>>(A2, B1, S1, out, N, M);
        // dist2: queries = input2 (B2,S2), targets = input1 (A1)
        dim3 g2(P2 / QPB, N / TSLICE);
        chamfer_mfma_kernel<<<g2, 256, 0, stream>>>(A1, B2, S2, out + P1, M, N);
    } else {
        hipMemsetAsync(d_out, 0x7F, (size_t)out_size * sizeof(float), stream);
        dim3 g1(P1 / FROWS, M / FSLICE);
        chamfer_dir_kernel<<<g1, 256, 0, stream>>>(in1, in2, out, N, M);
        dim3 g2(P2 / FROWS, N / FSLICE);
        chamfer_dir_kernel<<<g2, 256, 0, stream>>>(in2, in1, out + P1, M, N);
    }
}

// Round 5
// 61.298 us; speedup vs baseline: 2.1753x; 1.1349x over previous
//
#include <hip/hip_runtime.h>

// Chamfer distance via bf16 split-MFMA.
//   d(p,q') = ||p||^2 + (||q'||^2 - 2 p.q')
// Rank-16 GEMM in bf16 hi/lo-split form; one v_mfma_f32_32x32x16_bf16 =
// 32 targets x 32 queries = 1024 pairs, folded by 8 explicit v_min3_f32
// (inline asm -- clang won't fuse fminf chains to min3 without fast-math,
// and unfused folds + AGPR copies made round-4's kernel ~31us vs ~5 model).
// Both directions fused in one kernel (grid.z), both packs + sentinel init
// fused in one kernel: 2 launches total.

typedef __attribute__((ext_vector_type(8))) short  s16x8;
typedef __attribute__((ext_vector_type(16))) float f32x16;

#define TSLICE 1024   // targets staged in LDS per block (32 KB packed)
#define QPB    512    // queries per block (4 waves x 128)
#define QPW    128    // queries per wave (4 frags of 32)

__device__ inline float min3f(float a, float b, float c) {
    float r;
    asm("v_min3_f32 %0, %1, %2, %3" : "=v"(r) : "v"(a), "v"(b), "v"(c));
    return r;
}

// ---------- bf16 split helper (bit-level, RNE) ----------
__device__ inline unsigned int bf16bits(float v, float &hival) {
    unsigned int u = __float_as_uint(v);
    unsigned int r = (u + 0x7FFFu + ((u >> 16) & 1u)) >> 16;
    hival = __uint_as_float(r << 16);
    return r;
}

// ---------- fused pre-pass: pack both inputs + sentinel-init d_out ----------
__global__ __launch_bounds__(256)
void pack_all_kernel(const float* __restrict__ in1, const float* __restrict__ in2,
                     ushort* __restrict__ A1, ushort* __restrict__ B1, float* __restrict__ S1,
                     ushort* __restrict__ A2, ushort* __restrict__ B2, float* __restrict__ S2,
                     unsigned int* __restrict__ out, int P1, int P2) {
    const int g = blockIdx.x * 256 + threadIdx.x;
    if (g >= P1 + P2) return;
    out[g] = 0x7F7F7F7Fu;                 // 3.39e38f sentinel (flat over both outs)

    const float* src; ushort* pA; ushort* pB; float* sq; int p;
    if (g < P1) { src = in1; pA = A1; pB = B1; sq = S1; p = g; }
    else        { src = in2; pA = A2; pB = B2; sq = S2; p = g - P1; }

    const float x = src[3*p+0], y = src[3*p+1], z = src[3*p+2];
    float xhf, xlf, yhf, ylf, zhf, zlf, shf, tmp;
    const ushort xh = (ushort)bf16bits(x, xhf);
    const ushort xl = (ushort)bf16bits(x - xhf, xlf);
    const ushort yh = (ushort)bf16bits(y, yhf);
    const ushort yl = (ushort)bf16bits(y - yhf, ylf);
    const ushort zh = (ushort)bf16bits(z, zhf);
    const ushort zl = (ushort)bf16bits(z - zhf, zlf);
    const float s = fmaf(x, x, fmaf(y, y, z * z));
    const ushort sh = (ushort)bf16bits(s, shf);
    const ushort sl = (ushort)bf16bits(s - shf, tmp);
    const ushort m2xh = (ushort)bf16bits(-2.0f * xhf, tmp);
    const ushort m2xl = (ushort)bf16bits(-2.0f * xlf, tmp);
    const ushort m2yh = (ushort)bf16bits(-2.0f * yhf, tmp);
    const ushort m2yl = (ushort)bf16bits(-2.0f * ylf, tmp);
    const ushort m2zh = (ushort)bf16bits(-2.0f * zhf, tmp);
    const ushort m2zl = (ushort)bf16bits(-2.0f * zlf, tmp);
    const ushort ONE = 0x3F80;

    const s16x8 a0 = {(short)m2xh,(short)m2xl,(short)m2xh,(short)m2xl,
                      (short)m2yh,(short)m2yl,(short)m2yh,(short)m2yl};
    const s16x8 a1 = {(short)m2zh,(short)m2zl,(short)m2zh,(short)m2zl,
                      (short)sh,  (short)sl,  0, 0};
    const s16x8 b0 = {(short)xh,(short)xh,(short)xl,(short)xl,
                      (short)yh,(short)yh,(short)yl,(short)yl};
    const s16x8 b1 = {(short)zh,(short)zh,(short)zl,(short)zl,
                      (short)ONE,(short)ONE, 0, 0};

    s16x8* A8 = (s16x8*)pA;
    s16x8* B8 = (s16x8*)pB;
    // A: fragment-linear per 32-target tile: chunk = tilebase*64 + khalf*32 + row
    const int c0 = (p & ~31) * 2 + (p & 31);
    A8[c0]      = a0;   // k-slots 0-7  (lanes 0-31)
    A8[c0 + 32] = a1;   // k-slots 8-15 (lanes 32-63)
    // B: point-major
    B8[2*p]     = b0;
    B8[2*p + 1] = b1;
    sq[p] = s;
}

// ---------- main MFMA kernel, both directions (blockIdx.z selects) ----------
__global__ __launch_bounds__(256)
void chamfer_mfma_kernel(const ushort* __restrict__ Ad1, const ushort* __restrict__ Bd1,
                         const float*  __restrict__ Sd1, unsigned int* __restrict__ Od1,
                         const ushort* __restrict__ Ad2, const ushort* __restrict__ Bd2,
                         const float*  __restrict__ Sd2, unsigned int* __restrict__ Od2,
                         int Np, int Mp) {
    __shared__ s16x8 lds8[TSLICE * 2];   // 32 KB
    const int z = blockIdx.z;
    const ushort* pA  = z ? Ad2 : Ad1;
    const ushort* pB  = z ? Bd2 : Bd1;
    const float*  sqq = z ? Sd2 : Sd1;
    unsigned int* out = z ? Od2 : Od1;

    const int tid  = threadIdx.x;
    const int lane = tid & 63;
    const int wid  = tid >> 6;
    const int qblock = blockIdx.x * QPB;        // flat over B*Np (QPB | Np)
    const int b = qblock / Np;
    const size_t gchunk = ((size_t)b * Mp + (size_t)blockIdx.y * TSLICE) * 2;
    const s16x8* gA = (const s16x8*)pA + gchunk;
    for (int i = tid; i < TSLICE * 2; i += 256) lds8[i] = gA[i];

    // B fragments: 4 x 32 queries, loop-invariant in registers
    const int qw = qblock + wid * QPW;
    s16x8 bfr[4];
    #pragma unroll
    for (int f = 0; f < 4; ++f) {
        const int q = qw + f * 32 + (lane & 31);
        bfr[f] = *(const s16x8*)(pB + (size_t)q * 16 + (size_t)(lane >> 5) * 8);
    }
    __syncthreads();

    const f32x16 cz = {0.f,0.f,0.f,0.f,0.f,0.f,0.f,0.f,
                       0.f,0.f,0.f,0.f,0.f,0.f,0.f,0.f};
    float bests[4] = {3.0e38f, 3.0e38f, 3.0e38f, 3.0e38f};

    const int NT = TSLICE / 32;
    for (int t = 0; t < NT; ++t) {
        const s16x8 a = lds8[t * 64 + lane];
        #pragma unroll
        for (int f = 0; f < 4; ++f) {
            const f32x16 d = __builtin_amdgcn_mfma_f32_32x32x16_bf16(a, bfr[f], cz, 0, 0, 0);
            // 16 -> 1 in exactly 8 v_min3_f32 (incl. merge with running best)
            const float m0 = min3f(d[0],  d[1],  d[2]);
            const float m1 = min3f(d[3],  d[4],  d[5]);
            const float m2 = min3f(d[6],  d[7],  d[8]);
            const float m3 = min3f(d[9],  d[10], d[11]);
            const float m4 = min3f(d[12], d[13], d[14]);
            const float m5 = min3f(m0, m1, d[15]);
            const float m6 = min3f(m2, m3, m4);
            bests[f] = min3f(m5, m6, bests[f]);
        }
    }

    #pragma unroll
    for (int f = 0; f < 4; ++f) {
        float v = fminf(bests[f], __shfl_xor(bests[f], 32));  // merge row halves
        const int q = qw + f * 32 + (lane & 31);
        v = fmaxf(v + sqq[q], 0.0f);                          // clamp: keep >= 0
        if (lane < 32) atomicMin(out + q, __float_as_uint(v));
    }
}

// ---------- fallback (round-2 VALU kernel) if ws too small ----------
#define FSLICE 512
#define FROWS  512
__global__ __launch_bounds__(256)
void chamfer_dir_kernel(const float* __restrict__ P, const float* __restrict__ Q,
                        unsigned int* __restrict__ out, int Np, int Mp) {
    __shared__ float4 lds[FSLICE];
    const int tid = threadIdx.x;
    const int rowBase = blockIdx.x * FROWS;
    const int b = rowBase / Np;
    const int slice0 = blockIdx.y * FSLICE;
    const float* qs = Q + ((size_t)b * Mp + slice0) * 3;
    #pragma unroll
    for (int i = tid; i < FSLICE; i += 256) {
        const float x = qs[3*i+0], y = qs[3*i+1], z = qs[3*i+2];
        lds[i] = make_float4(x, y, z, fmaf(x, x, fmaf(y, y, z * z)));
    }
    const int q0 = rowBase + tid, q1 = q0 + 256;
    const float* p0 = P + (size_t)q0 * 3;
    const float* p1 = P + (size_t)q1 * 3;
    const float x0=p0[0], y0=p0[1], z0=p0[2], x1=p1[0], y1=p1[1], z1=p1[2];
    const float m2x0=-2*x0, m2y0=-2*y0, m2z0=-2*z0, m2x1=-2*x1, m2y1=-2*y1, m2z1=-2*z1;
    const float sqp0 = fmaf(x0,x0,fmaf(y0,y0,z0*z0));
    const float sqp1 = fmaf(x1,x1,fmaf(y1,y1,z1*z1));
    __syncthreads();
    float best0 = 3.0e38f, best1 = 3.0e38f;
    #pragma unroll 4
    for (int j = 0; j < FSLICE; j += 2) {
        const float4 a = lds[j], c = lds[j+1];
        const float d00 = fmaf(m2x0,a.x,fmaf(m2y0,a.y,fmaf(m2z0,a.z,a.w)));
        const float d01 = fmaf(m2x0,c.x,fmaf(m2y0,c.y,fmaf(m2z0,c.z,c.w)));
        best0 = fminf(fminf(d00,d01), best0);
        const float d10 = fmaf(m2x1,a.x,fmaf(m2y1,a.y,fmaf(m2z1,a.z,a.w)));
        const float d11 = fmaf(m2x1,c.x,fmaf(m2y1,c.y,fmaf(m2z1,c.z,c.w)));
        best1 = fminf(fminf(d10,d11), best1);
    }
    atomicMin(out + q0, __float_as_uint(fmaxf(best0 + sqp0, 0.f)));
    atomicMin(out + q1, __float_as_uint(fmaxf(best1 + sqp1, 0.f)));
}

extern "C" void kernel_launch(void* const* d_in, const int* in_sizes, int n_in,
                              void* d_out, int out_size, void* d_ws, size_t ws_size,
                              hipStream_t stream) {
    const float* in1 = (const float*)d_in[0];   // [B, N, 3]
    const float* in2 = (const float*)d_in[1];   // [B, M, 3]
    const int B = 8;
    const int N = in_sizes[0] / (B * 3);
    const int M = in_sizes[1] / (B * 3);
    const int P1 = B * N, P2 = B * M;
    unsigned int* out = (unsigned int*)d_out;

    const size_t packBytes1 = (size_t)P1 * 32, packBytes2 = (size_t)P2 * 32;
    const size_t need = 2*packBytes1 + 2*packBytes2 + (size_t)(P1+P2)*4;

    if (ws_size >= need && N == M) {
        char* w = (char*)d_ws;
        ushort* A1 = (ushort*)(w);
        ushort* B1 = (ushort*)(w + packBytes1);
        ushort* A2 = (ushort*)(w + 2*packBytes1);
        ushort* B2 = (ushort*)(w + 2*packBytes1 + packBytes2);
        float*  S1 = (float*) (w + 2*packBytes1 + 2*packBytes2);
        float*  S2 = (float*) (w + 2*packBytes1 + 2*packBytes2 + (size_t)P1*4);

        pack_all_kernel<<<(P1 + P2 + 255)/256, 256, 0, stream>>>(
            in1, in2, A1, B1, S1, A2, B2, S2, out, P1, P2);

        // z=0: dist1 (queries=input1, targets=input2); z=1: dist2
        dim3 g(P1 / QPB, M / TSLICE, 2);
        chamfer_mfma_kernel<<<g, 256, 0, stream>>>(
            A2, B1, S1, out,        // dir 1
            A1, B2, S2, out + P1,   // dir 2
            N, M);
    } else {
        hipMemsetAsync(d_out, 0x7F, (size_t)out_size * sizeof(float), stream);
        dim3 g1(P1 / FROWS, M / FSLICE);
        chamfer_dir_kernel<<<g1, 256, 0, stream>>>(in1, in2, out, N, M);
        dim3 g2(P2 / FROWS, N / FSLICE);
        chamfer_dir_kernel<<<g2, 256, 0, stream>>>(in2, in1, out + P1, M, N);
    }
}